// Round 8
// baseline (506.726 us; speedup 1.0000x reference)
//
#include <hip/hip_runtime.h>
#include <hip/hip_bf16.h>

#define N_NODES 100000
#define N_EDGES 1600000
// IN_CH=256, HID_CH=128, OUT_CH=64

typedef __attribute__((ext_vector_type(8))) short short8;
typedef __attribute__((ext_vector_type(8))) unsigned short u16x8;
typedef __attribute__((ext_vector_type(4))) unsigned short u16x4;
typedef __attribute__((ext_vector_type(4))) float f32x4;
typedef __attribute__((ext_vector_type(2))) int i32x2;

__device__ __forceinline__ unsigned short f2bf(float f) {
    union { float f; unsigned u; } v;
    v.f = f;
    unsigned r = v.u + 0x7FFFu + ((v.u >> 16) & 1u);  // RNE
    return (unsigned short)(r >> 16);
}
__device__ __forceinline__ float bf2f(unsigned short u) {
    union { unsigned u; float f; } v;
    v.u = (unsigned)u << 16;
    return v.f;
}

// ---------------- CSR build (1 atomic/edge, 1 random 8B write/edge) ----------------

// rank within destination bucket; counts accumulate in cnt
__global__ void count_rank(const int* __restrict__ dst, int* __restrict__ cnt,
                           int* __restrict__ erank) {
    int e = blockIdx.x * 256 + threadIdx.x;
    if (e < N_EDGES) erank[e] = atomicAdd(&cnt[dst[e]], 1);
}

__global__ __launch_bounds__(256) void scan1(const int* __restrict__ cnt,
                                             int* __restrict__ rowptr,
                                             int* __restrict__ bsum) {
    __shared__ int s[256];
    int tid = threadIdx.x;
    int i = blockIdx.x * 256 + tid;
    int v = (i < N_NODES) ? cnt[i] : 0;
    s[tid] = v;
    __syncthreads();
#pragma unroll
    for (int off = 1; off < 256; off <<= 1) {
        int t = (tid >= off) ? s[tid - off] : 0;
        __syncthreads();
        s[tid] += t;
        __syncthreads();
    }
    if (i < N_NODES) rowptr[i] = s[tid] - v;  // exclusive
    if (tid == 255) bsum[blockIdx.x] = s[255];
}

__global__ __launch_bounds__(512) void scan2(int* __restrict__ bsum, int nb) {
    __shared__ int s[512];
    int tid = threadIdx.x;
    int v = (tid < nb) ? bsum[tid] : 0;
    s[tid] = v;
    __syncthreads();
#pragma unroll
    for (int off = 1; off < 512; off <<= 1) {
        int t = (tid >= off) ? s[tid - off] : 0;
        __syncthreads();
        s[tid] += t;
        __syncthreads();
    }
    if (tid < nb) bsum[tid] = s[tid] - v;  // exclusive
}

__global__ void scan3(int* __restrict__ rowptr, const int* __restrict__ bsum) {
    int i = blockIdx.x * 256 + threadIdx.x;
    if (i < N_NODES) rowptr[i] += bsum[blockIdx.x];
    if (i == 0) rowptr[N_NODES] = N_EDGES;
}

// place packed {src, raw edge weight} at rowptr[dst]+rank — no atomics
__global__ void place(const int* __restrict__ src, const int* __restrict__ dst,
                      const float* __restrict__ ew, const int* __restrict__ rowptr,
                      const int* __restrict__ erank, int2* __restrict__ epack) {
    int e = blockIdx.x * 256 + threadIdx.x;
    if (e >= N_EDGES) return;
    int idx = rowptr[dst[e]] + erank[e];
    epack[idx] = make_int2(src[e], __float_as_int(ew[e]));
}

// per-node row-sum of raw weights -> dis = rsqrt(deg+1)  (self-loop adds 1)
__global__ void deg_dis(const int* __restrict__ rowptr, const int2* __restrict__ epack,
                        float* __restrict__ dis) {
    int n = blockIdx.x * 256 + threadIdx.x;
    if (n >= N_NODES) return;
    float sum = 1.0f;
    int end = rowptr[n + 1];
    for (int j = rowptr[n]; j < end; ++j) sum += __int_as_float(epack[j].y);
    dis[n] = rsqrtf(sum);
}

// ---------------- weight prep (fused): transpose + bf16 ----------------
// i<32768: W1T[n][k] = bf16(W1[k][n]); i<16384: WcatT[n][k] = Wmu|Wlv
__global__ void weights_prep(const float* __restrict__ W1, const float* __restrict__ Wmu,
                             const float* __restrict__ Wlv,
                             unsigned short* __restrict__ w1T,
                             unsigned short* __restrict__ wcatT) {
    int i = blockIdx.x * 256 + threadIdx.x;  // 0..32767
    {
        int k = i >> 7, n = i & 127;
        w1T[n * 256 + k] = f2bf(W1[i]);
    }
    if (i < 16384) {
        int n = i >> 7, k = i & 127;
        float v = (n < 64) ? Wmu[k * 64 + n] : Wlv[k * 64 + (n - 64)];
        wcatT[n * 128 + k] = f2bf(v);
    }
}

// ---------------- bf16 MFMA GEMM: C[M,128] = A[M,K] @ WT^T ----------------
// WT is [128][K] bf16 (pre-transposed). BM=64 (4 waves x 16 rows), BN=128, BK=32.
// C/D: col = lane&15, row = (lane>>4)*4 + reg  [m89 verified].
template <int K, bool A_BF16>
__global__ __launch_bounds__(256) void gemm_mfma(const void* __restrict__ Aptr,
                                                 const unsigned short* __restrict__ WT,
                                                 unsigned short* __restrict__ C, int M) {
    __shared__ unsigned short As[4 * 64 * 8];   // 4 KB
    __shared__ unsigned short Bs[4 * 128 * 8];  // 8 KB
    const int t = threadIdx.x;
    const int wave = t >> 6, lane = t & 63;
    const int l15 = lane & 15, l4 = lane >> 4;
    const int bm = blockIdx.x * 64;

    f32x4 acc[8] = {};

    const int ar = t >> 2;   // A staging row 0..63
    const int akb = t & 3;   // A staging k-block
    const int bn = t >> 1;   // B staging n 0..127

    for (int k0 = 0; k0 < K; k0 += 32) {
        {
            int row = bm + ar;
            u16x8 av = {};
            if (row < M) {
                if (A_BF16) {
                    av = *reinterpret_cast<const u16x8*>(
                        &((const unsigned short*)Aptr)[(long)row * K + k0 + akb * 8]);
                } else {
                    const float* Af = (const float*)Aptr;
                    float4 v0 = *reinterpret_cast<const float4*>(&Af[(long)row * K + k0 + akb * 8]);
                    float4 v1 = *reinterpret_cast<const float4*>(&Af[(long)row * K + k0 + akb * 8 + 4]);
                    av[0] = f2bf(v0.x); av[1] = f2bf(v0.y); av[2] = f2bf(v0.z); av[3] = f2bf(v0.w);
                    av[4] = f2bf(v1.x); av[5] = f2bf(v1.y); av[6] = f2bf(v1.z); av[7] = f2bf(v1.w);
                }
            }
            *reinterpret_cast<u16x8*>(&As[(akb * 64 + ar) * 8]) = av;
        }
#pragma unroll
        for (int c = 0; c < 2; ++c) {
            int kb = (t & 1) * 2 + c;
            u16x8 bv = *reinterpret_cast<const u16x8*>(&WT[(long)bn * K + k0 + kb * 8]);
            *reinterpret_cast<u16x8*>(&Bs[(kb * 128 + bn) * 8]) = bv;
        }
        __syncthreads();
        short8 a = *reinterpret_cast<const short8*>(&As[(l4 * 64 + wave * 16 + l15) * 8]);
#pragma unroll
        for (int f = 0; f < 8; ++f) {
            short8 b = *reinterpret_cast<const short8*>(&Bs[(l4 * 128 + f * 16 + l15) * 8]);
            acc[f] = __builtin_amdgcn_mfma_f32_16x16x32_bf16(a, b, acc[f], 0, 0, 0);
        }
        __syncthreads();
    }
#pragma unroll
    for (int f = 0; f < 8; ++f) {
#pragma unroll
        for (int r = 0; r < 4; ++r) {
            int row = bm + wave * 16 + l4 * 4 + r;
            if (row < M) C[(long)row * 128 + f * 16 + l15] = f2bf(acc[f][r]);
        }
    }
}

// ---------------- gather-reduce convs (bf16 messages, fused norm) ----------------
// 32 lanes per node, 4 channels (8 B) per lane. norm = dis[src]*ew*dis[dst] on the
// fly (dis L2-resident). 4-edge unroll: 4 independent row loads in flight per lane
// (latency hiding). epack streamed with nontemporal loads (read once — don't evict
// feature rows from L2); outputs nontemporal stores (no L2 allocation needed).

__global__ __launch_bounds__(256) void gather_conv1(
    const int* __restrict__ rowptr, const int2* __restrict__ epack,
    const unsigned short* __restrict__ hlin, const float* __restrict__ dis,
    const float* __restrict__ bias, unsigned short* __restrict__ hout) {
    int tid = blockIdx.x * 256 + threadIdx.x;  // N_NODES*32
    int n = tid >> 5, q = tid & 31;
    float dv = dis[n], s2 = dv * dv;
    float4 b = *reinterpret_cast<const float4*>(&bias[q * 4]);
    u16x4 sv = *reinterpret_cast<const u16x4*>(&hlin[(long)n * 128 + q * 4]);
    float a0 = bf2f(sv[0]) * s2 + b.x;
    float a1 = bf2f(sv[1]) * s2 + b.y;
    float a2 = bf2f(sv[2]) * s2 + b.z;
    float a3 = bf2f(sv[3]) * s2 + b.w;

    int j = rowptr[n], end = rowptr[n + 1];
    for (; j + 4 <= end; j += 4) {
        i32x2 p0 = __builtin_nontemporal_load((const i32x2*)(epack + j));
        i32x2 p1 = __builtin_nontemporal_load((const i32x2*)(epack + j + 1));
        i32x2 p2 = __builtin_nontemporal_load((const i32x2*)(epack + j + 2));
        i32x2 p3 = __builtin_nontemporal_load((const i32x2*)(epack + j + 3));
        u16x4 m0 = *reinterpret_cast<const u16x4*>(&hlin[(long)p0.x * 128 + q * 4]);
        u16x4 m1 = *reinterpret_cast<const u16x4*>(&hlin[(long)p1.x * 128 + q * 4]);
        u16x4 m2 = *reinterpret_cast<const u16x4*>(&hlin[(long)p2.x * 128 + q * 4]);
        u16x4 m3 = *reinterpret_cast<const u16x4*>(&hlin[(long)p3.x * 128 + q * 4]);
        float w0 = dis[p0.x] * __int_as_float(p0.y) * dv;
        float w1 = dis[p1.x] * __int_as_float(p1.y) * dv;
        float w2 = dis[p2.x] * __int_as_float(p2.y) * dv;
        float w3 = dis[p3.x] * __int_as_float(p3.y) * dv;
        a0 += bf2f(m0[0]) * w0 + bf2f(m1[0]) * w1 + bf2f(m2[0]) * w2 + bf2f(m3[0]) * w3;
        a1 += bf2f(m0[1]) * w0 + bf2f(m1[1]) * w1 + bf2f(m2[1]) * w2 + bf2f(m3[1]) * w3;
        a2 += bf2f(m0[2]) * w0 + bf2f(m1[2]) * w1 + bf2f(m2[2]) * w2 + bf2f(m3[2]) * w3;
        a3 += bf2f(m0[3]) * w0 + bf2f(m1[3]) * w1 + bf2f(m2[3]) * w2 + bf2f(m3[3]) * w3;
    }
    for (; j < end; ++j) {
        i32x2 p0 = __builtin_nontemporal_load((const i32x2*)(epack + j));
        float w0 = dis[p0.x] * __int_as_float(p0.y) * dv;
        u16x4 m0 = *reinterpret_cast<const u16x4*>(&hlin[(long)p0.x * 128 + q * 4]);
        a0 += bf2f(m0[0]) * w0; a1 += bf2f(m0[1]) * w0;
        a2 += bf2f(m0[2]) * w0; a3 += bf2f(m0[3]) * w0;
    }
    // fused ReLU + bf16 pack (feeds GEMM2 directly)
    u16x4 o;
    o[0] = f2bf(fmaxf(a0, 0.f)); o[1] = f2bf(fmaxf(a1, 0.f));
    o[2] = f2bf(fmaxf(a2, 0.f)); o[3] = f2bf(fmaxf(a3, 0.f));
    __builtin_nontemporal_store(o, reinterpret_cast<u16x4*>(&hout[(long)n * 128 + q * 4]));
}

// conv2: g[n][0:64] -> mu, g[n][64:128] -> logvar (f32 outputs)
__global__ __launch_bounds__(256) void gather_conv2(
    const int* __restrict__ rowptr, const int2* __restrict__ epack,
    const unsigned short* __restrict__ g, const float* __restrict__ dis,
    const float* __restrict__ bmu, const float* __restrict__ blv,
    float* __restrict__ outmu, float* __restrict__ outlv) {
    int tid = blockIdx.x * 256 + threadIdx.x;  // N_NODES*32
    int n = tid >> 5, q = tid & 31;
    float dv = dis[n], s2 = dv * dv;
    float4 b = (q < 16) ? *reinterpret_cast<const float4*>(&bmu[q * 4])
                        : *reinterpret_cast<const float4*>(&blv[(q - 16) * 4]);
    u16x4 sv = *reinterpret_cast<const u16x4*>(&g[(long)n * 128 + q * 4]);
    float a0 = bf2f(sv[0]) * s2 + b.x;
    float a1 = bf2f(sv[1]) * s2 + b.y;
    float a2 = bf2f(sv[2]) * s2 + b.z;
    float a3 = bf2f(sv[3]) * s2 + b.w;

    int j = rowptr[n], end = rowptr[n + 1];
    for (; j + 4 <= end; j += 4) {
        i32x2 p0 = __builtin_nontemporal_load((const i32x2*)(epack + j));
        i32x2 p1 = __builtin_nontemporal_load((const i32x2*)(epack + j + 1));
        i32x2 p2 = __builtin_nontemporal_load((const i32x2*)(epack + j + 2));
        i32x2 p3 = __builtin_nontemporal_load((const i32x2*)(epack + j + 3));
        u16x4 m0 = *reinterpret_cast<const u16x4*>(&g[(long)p0.x * 128 + q * 4]);
        u16x4 m1 = *reinterpret_cast<const u16x4*>(&g[(long)p1.x * 128 + q * 4]);
        u16x4 m2 = *reinterpret_cast<const u16x4*>(&g[(long)p2.x * 128 + q * 4]);
        u16x4 m3 = *reinterpret_cast<const u16x4*>(&g[(long)p3.x * 128 + q * 4]);
        float w0 = dis[p0.x] * __int_as_float(p0.y) * dv;
        float w1 = dis[p1.x] * __int_as_float(p1.y) * dv;
        float w2 = dis[p2.x] * __int_as_float(p2.y) * dv;
        float w3 = dis[p3.x] * __int_as_float(p3.y) * dv;
        a0 += bf2f(m0[0]) * w0 + bf2f(m1[0]) * w1 + bf2f(m2[0]) * w2 + bf2f(m3[0]) * w3;
        a1 += bf2f(m0[1]) * w0 + bf2f(m1[1]) * w1 + bf2f(m2[1]) * w2 + bf2f(m3[1]) * w3;
        a2 += bf2f(m0[2]) * w0 + bf2f(m1[2]) * w1 + bf2f(m2[2]) * w2 + bf2f(m3[2]) * w3;
        a3 += bf2f(m0[3]) * w0 + bf2f(m1[3]) * w1 + bf2f(m2[3]) * w2 + bf2f(m3[3]) * w3;
    }
    for (; j < end; ++j) {
        i32x2 p0 = __builtin_nontemporal_load((const i32x2*)(epack + j));
        float w0 = dis[p0.x] * __int_as_float(p0.y) * dv;
        u16x4 m0 = *reinterpret_cast<const u16x4*>(&g[(long)p0.x * 128 + q * 4]);
        a0 += bf2f(m0[0]) * w0; a1 += bf2f(m0[1]) * w0;
        a2 += bf2f(m0[2]) * w0; a3 += bf2f(m0[3]) * w0;
    }
    f32x4 o = {a0, a1, a2, a3};
    if (q < 16)
        __builtin_nontemporal_store(o, reinterpret_cast<f32x4*>(&outmu[(long)n * 64 + q * 4]));
    else
        __builtin_nontemporal_store(o, reinterpret_cast<f32x4*>(&outlv[(long)n * 64 + (q - 16) * 4]));
}

// ---------------- launch ----------------

extern "C" void kernel_launch(void* const* d_in, const int* in_sizes, int n_in,
                              void* d_out, int out_size, void* d_ws, size_t ws_size,
                              hipStream_t stream) {
    const float* x   = (const float*)d_in[0];
    const int*   ei  = (const int*)d_in[1];
    const float* ew  = (const float*)d_in[2];
    const float* W1  = (const float*)d_in[3];
    const float* b1  = (const float*)d_in[4];
    const float* Wmu = (const float*)d_in[5];
    const float* bmu = (const float*)d_in[6];
    const float* Wlv = (const float*)d_in[7];
    const float* blv = (const float*)d_in[8];

    const int* srcI = ei;            // edge_index[0]
    const int* dstI = ei + N_EDGES;  // edge_index[1]

    float* ws = (float*)d_ws;
    float*          dis    = ws;                               // 100352
    int*            cnt    = (int*)(ws + 100352);              // 100352
    int*            rowptr = (int*)(ws + 200704);              // 100352 (needs 100001)
    int*            bsum   = (int*)(ws + 301056);              // 512
    int*            erank  = (int*)(ws + 301568);              // 1600000
    int2*           epack  = (int2*)(ws + 1901568);            // 1600000 int2 (8B-aligned)
    unsigned short* w1T    = (unsigned short*)(ws + 5101568);  // 32768 ush
    unsigned short* wcatT  = (unsigned short*)(ws + 5117952);  // 16384 ush
    unsigned short* hlin   = (unsigned short*)(ws + 5126144);  // 12.8M ush
    unsigned short* h      = (unsigned short*)(ws + 11526144); // 12.8M ush (ends ~72 MB)
    unsigned short* g      = hlin;  // reuse: hlin dead after gather_conv1
    float* outmu = (float*)d_out;
    float* outlv = outmu + (long)N_NODES * 64;

    const int NB = (N_NODES + 255) / 256;  // 391
    const int EB = N_EDGES / 256;          // 6250

    hipMemsetAsync(cnt, 0, N_NODES * sizeof(int), stream);

    // CSR build: 1 atomic/edge (count_rank), 1 random 8B write/edge (place)
    count_rank<<<EB, 256, 0, stream>>>(dstI, cnt, erank);
    scan1<<<NB, 256, 0, stream>>>(cnt, rowptr, bsum);
    scan2<<<1, 512, 0, stream>>>(bsum, NB);
    scan3<<<NB, 256, 0, stream>>>(rowptr, bsum);
    place<<<EB, 256, 0, stream>>>(srcI, dstI, ew, rowptr, erank, epack);
    deg_dis<<<NB, 256, 0, stream>>>(rowptr, epack, dis);

    weights_prep<<<128, 256, 0, stream>>>(W1, Wmu, Wlv, w1T, wcatT);

    // layer 1
    gemm_mfma<256, false><<<(N_NODES + 63) / 64, 256, 0, stream>>>(x, w1T, hlin, N_NODES);
    gather_conv1<<<N_NODES * 32 / 256, 256, 0, stream>>>(rowptr, epack, hlin, dis, b1, h);
    // layer 2 (mu | logvar fused)
    gemm_mfma<128, true><<<(N_NODES + 63) / 64, 256, 0, stream>>>(h, wcatT, g, N_NODES);
    gather_conv2<<<N_NODES * 32 / 256, 256, 0, stream>>>(rowptr, epack, g, dis,
                                                         bmu, blv, outmu, outlv);
}